// Round 1
// baseline (197.788 us; speedup 1.0000x reference)
//
#include <hip/hip_runtime.h>
#include <stdint.h>

// ---------------------------------------------------------------------------
// GeometricAttention: x@Wqkv -> RoPE -> causal MHA -> @Wo -> blade mixing
// B=2 T=2048 N=8 D=128, d_model=1024. bf16 MFMA pipeline, fp32 accum.
// ---------------------------------------------------------------------------

typedef __attribute__((ext_vector_type(8))) __bf16 bf16x8;
typedef __attribute__((ext_vector_type(4))) float  f32x4;

__device__ __forceinline__ uint16_t f2bf(float f) {
    uint32_t u = __float_as_uint(f);
    u += 0x7FFFu + ((u >> 16) & 1u);           // RNE
    return (uint16_t)(u >> 16);
}
__device__ __forceinline__ float bf2f(uint16_t h) {
    return __uint_as_float(((uint32_t)h) << 16);
}

__device__ __forceinline__ void gload_lds16(const void* g, void* l) {
    __builtin_amdgcn_global_load_lds(
        (__attribute__((address_space(1))) void*)g,
        (__attribute__((address_space(3))) void*)l, 16, 0, 0);
}

__device__ __forceinline__ void store_out(uint16_t* p, float v) { *p = f2bf(v); }
__device__ __forceinline__ void store_out(float* p, float v)    { *p = v; }

// ---------------------------------------------------------------- cast fp32->bf16
__global__ __launch_bounds__(256) void k_cast(const float* __restrict__ in,
                                              uint16_t* __restrict__ out, int n) {
    int i = blockIdx.x * 256 + threadIdx.x;          // one float4 per thread
    if (i * 4 >= n) return;
    float4 v = ((const float4*)in)[i];
    ushort4 o = make_ushort4(f2bf(v.x), f2bf(v.y), f2bf(v.z), f2bf(v.w));
    ((ushort4*)out)[i] = o;
}

// ------------------------------------------------- transpose W [K][N] -> Wt [N][K] bf16
__global__ __launch_bounds__(256) void k_wtrans(const float* __restrict__ W,
                                                uint16_t* __restrict__ Wt,
                                                int K, int N) {
    __shared__ uint16_t tile[64][65];
    const int k0 = blockIdx.y * 64, n0 = blockIdx.x * 64;
    const int c = threadIdx.x & 63, r4 = threadIdx.x >> 6;
#pragma unroll
    for (int i = 0; i < 16; ++i) {
        int r = r4 + i * 4;
        tile[r][c] = f2bf(W[(size_t)(k0 + r) * N + n0 + c]);
    }
    __syncthreads();
#pragma unroll
    for (int i = 0; i < 16; ++i) {
        int r = r4 + i * 4;
        Wt[(size_t)(n0 + r) * K + k0 + c] = tile[c][r];
    }
}

// ---------------------------------------------------------------- RoPE tables
__global__ __launch_bounds__(256) void k_tab(float* __restrict__ ct,
                                             float* __restrict__ st) {
    int i = blockIdx.x * 256 + threadIdx.x;          // 2048*64
    int t = i >> 6, f = i & 63;
    float inv = expf(-(float)f * 0.14391156830441f); // ln(10000)/64
    float ang = (float)t * inv;
    ct[i] = cosf(ang);
    st[i] = sinf(ang);
}

// ------------------------------------------------------- m97-style bf16 GEMM
// C[M][N] = A[M][K] * Bt[N][K]^T ; 128x128 tile, BK=32, 4 waves
template <typename OutT>
__global__ __launch_bounds__(256) void k_gemm(const uint16_t* __restrict__ A,
                                              const uint16_t* __restrict__ Bt,
                                              OutT* __restrict__ C,
                                              int M, int N, int K) {
    __shared__ uint16_t Atile[128 * 32];
    __shared__ uint16_t Btile[128 * 32];
    const int m0 = blockIdx.y << 7, n0 = blockIdx.x << 7;
    const int tid = threadIdx.x;
    const int l = tid & 63, w = tid >> 6;
    const int lr = l & 15, lg = l >> 4;
    const int wm = (w >> 1) << 6, wn = (w & 1) << 6;

    f32x4 acc[4][4];
#pragma unroll
    for (int i = 0; i < 4; ++i)
#pragma unroll
        for (int j = 0; j < 4; ++j) acc[i][j] = (f32x4){0.f, 0.f, 0.f, 0.f};

    const int nk = K >> 5;
    for (int kt = 0; kt < nk; ++kt) {
        const int k0 = kt << 5;
        __syncthreads();
#pragma unroll
        for (int c = 0; c < 4; ++c) {
            int idx = c * 256 + tid;                 // 0..1023, wave-contiguous
            if (idx < 512) {
                int r = idx >> 2, kc = (idx & 3) << 3;
                gload_lds16(A + (size_t)(m0 + r) * K + k0 + kc, &Atile[idx * 8]);
            } else {
                int i2 = idx - 512;
                int r = i2 >> 2, kc = (i2 & 3) << 3;
                gload_lds16(Bt + (size_t)(n0 + r) * K + k0 + kc, &Btile[i2 * 8]);
            }
        }
        __syncthreads();
        bf16x8 af[4], bfv[4];
#pragma unroll
        for (int i = 0; i < 4; ++i) {
            af[i]  = *(const bf16x8*)(&Atile[(wm + i * 16 + lr) * 32 + lg * 8]);
            bfv[i] = *(const bf16x8*)(&Btile[(wn + i * 16 + lr) * 32 + lg * 8]);
        }
#pragma unroll
        for (int mi = 0; mi < 4; ++mi)
#pragma unroll
            for (int ni = 0; ni < 4; ++ni)
                acc[mi][ni] = __builtin_amdgcn_mfma_f32_16x16x32_bf16(
                    af[mi], bfv[ni], acc[mi][ni], 0, 0, 0);
    }
    // C/D layout: col = lane&15, row = (lane>>4)*4 + reg   [m89-verified]
#pragma unroll
    for (int mi = 0; mi < 4; ++mi)
#pragma unroll
        for (int ni = 0; ni < 4; ++ni)
#pragma unroll
            for (int r = 0; r < 4; ++r) {
                int row = m0 + wm + mi * 16 + lg * 4 + r;
                int col = n0 + wn + ni * 16 + lr;
                store_out(&C[(size_t)row * N + col], acc[mi][ni][r]);
            }
}

// ------------------------------------------- RoPE apply: QKV -> Q,K [h][T][D]
__global__ __launch_bounds__(256) void k_rope(const uint16_t* __restrict__ qkv,
                                              const float* __restrict__ ct,
                                              const float* __restrict__ st,
                                              uint16_t* __restrict__ Qo,
                                              uint16_t* __restrict__ Ko) {
    int idx = blockIdx.x * 256 + threadIdx.x;        // B*T*N*64 pairs
    int d  = idx & 63;
    int n  = (idx >> 6) & 7;
    int bt = idx >> 9;
    int t  = bt & 2047, b = bt >> 11;
    float c = ct[t * 64 + d], s = st[t * 64 + d];
    size_t base = (size_t)bt * 3072 + n * 128 + d;
    float q1 = bf2f(qkv[base]),        q2 = bf2f(qkv[base + 64]);
    float k1 = bf2f(qkv[base + 1024]), k2 = bf2f(qkv[base + 1024 + 64]);
    size_t ob = ((size_t)(b * 8 + n) * 2048 + t) * 128 + d;
    Qo[ob]      = f2bf(q1 * c - q2 * s);
    Qo[ob + 64] = f2bf(q2 * c + q1 * s);
    Ko[ob]      = f2bf(k1 * c - k2 * s);
    Ko[ob + 64] = f2bf(k2 * c + k1 * s);
}

// -------------------------------------- V transpose: QKV v-part -> Vt [h][D][T]
__global__ __launch_bounds__(256) void k_vtrans(const uint16_t* __restrict__ qkv,
                                                uint16_t* __restrict__ Vt) {
    __shared__ uint16_t tile[64][65];
    const int h = blockIdx.z, b = h >> 3, n = h & 7;
    const int t0 = blockIdx.y * 64, d0 = blockIdx.x * 64;
    const int c = threadIdx.x & 63, r4 = threadIdx.x >> 6;
#pragma unroll
    for (int i = 0; i < 16; ++i) {
        int r = r4 + i * 4;                          // t offset
        tile[r][c] = qkv[(size_t)(b * 2048 + t0 + r) * 3072 + 2048 + n * 128 + d0 + c];
    }
    __syncthreads();
#pragma unroll
    for (int i = 0; i < 16; ++i) {
        int r = r4 + i * 4;                          // d offset
        Vt[((size_t)h * 128 + d0 + r) * 2048 + t0 + c] = tile[c][r];
    }
}

// --------------------------------------------------- causal flash attention
// 64 q-rows/block, 4 waves x 16 rows; KV tiles of 64; online softmax
__global__ __launch_bounds__(256) void k_attn(const uint16_t* __restrict__ Qg,
                                              const uint16_t* __restrict__ Kg,
                                              const uint16_t* __restrict__ Vtg,
                                              uint16_t* __restrict__ AOg) {
    __shared__ uint16_t Klds[64 * 136];              // +8 pad: 2-way banks (free)
    __shared__ uint16_t Vlds[128 * 72];
    __shared__ uint16_t Plds[4][16 * 72];

    const int bx = blockIdx.x;
    const int h = bx >> 5, qt = 31 - (bx & 31);      // heavy tiles first
    const int q0 = qt * 64;
    const int tid = threadIdx.x;
    const int l = tid & 63, w = tid >> 6;
    const int lr = l & 15, lg = l >> 4;
    const size_t headTD = (size_t)h * (2048 * 128);

    bf16x8 qf[4];
    {
        const uint16_t* qp = Qg + headTD + (size_t)(q0 + w * 16 + lr) * 128 + lg * 8;
#pragma unroll
        for (int kc = 0; kc < 4; ++kc) qf[kc] = *(const bf16x8*)(qp + kc * 32);
    }

    f32x4 accO[8];
#pragma unroll
    for (int i = 0; i < 8; ++i) accO[i] = (f32x4){0.f, 0.f, 0.f, 0.f};
    float mrun[4], lrun[4];
#pragma unroll
    for (int r = 0; r < 4; ++r) { mrun[r] = -1e30f; lrun[r] = 0.f; }

    const float scale = 0.08838834764831845f;        // 1/sqrt(128)
    const float L2E   = 1.4426950408889634f;

    for (int kt = 0; kt <= qt; ++kt) {
        const int k0 = kt * 64;
        __syncthreads();
#pragma unroll
        for (int p = 0; p < 4; ++p) {                // K tile 64x128
            int idx = p * 256 + tid;
            int r = idx >> 4, c8 = (idx & 15) << 3;
            *(bf16x8*)(&Klds[r * 136 + c8]) =
                *(const bf16x8*)(Kg + headTD + (size_t)(k0 + r) * 128 + c8);
        }
#pragma unroll
        for (int p = 0; p < 4; ++p) {                // Vt tile 128x64
            int idx = p * 256 + tid;
            int r = idx >> 3, c8 = (idx & 7) << 3;
            *(bf16x8*)(&Vlds[r * 72 + c8]) =
                *(const bf16x8*)(Vtg + headTD + (size_t)r * 2048 + k0 + c8);
        }
        __syncthreads();

        // S = Q K^T  (16x64 per wave)
        float sv[4][4];
#pragma unroll
        for (int cg = 0; cg < 4; ++cg) {
            f32x4 a = (f32x4){0.f, 0.f, 0.f, 0.f};
#pragma unroll
            for (int kc = 0; kc < 4; ++kc) {
                bf16x8 kf = *(const bf16x8*)(&Klds[(cg * 16 + lr) * 136 + kc * 32 + lg * 8]);
                a = __builtin_amdgcn_mfma_f32_16x16x32_bf16(qf[kc], kf, a, 0, 0, 0);
            }
#pragma unroll
            for (int r = 0; r < 4; ++r) sv[cg][r] = a[r] * scale;
        }
        if (kt == qt) {                              // causal mask on diagonal tile
#pragma unroll
            for (int cg = 0; cg < 4; ++cg)
#pragma unroll
                for (int r = 0; r < 4; ++r) {
                    int grow = w * 16 + lg * 4 + r;
                    int gcol = cg * 16 + lr;
                    if (gcol > grow) sv[cg][r] = -1e30f;
                }
        }
        // row max over 64 cols: 4-acc max + 16-lane butterfly
        float mnew[4];
#pragma unroll
        for (int r = 0; r < 4; ++r)
            mnew[r] = fmaxf(fmaxf(sv[0][r], sv[1][r]), fmaxf(sv[2][r], sv[3][r]));
#pragma unroll
        for (int off = 1; off < 16; off <<= 1)
#pragma unroll
            for (int r = 0; r < 4; ++r)
                mnew[r] = fmaxf(mnew[r], __shfl_xor(mnew[r], off, 64));

        float corr[4], lnew[4];
#pragma unroll
        for (int r = 0; r < 4; ++r) {
            float mc = fmaxf(mrun[r], mnew[r]);
            corr[r] = exp2f((mrun[r] - mc) * L2E);
            mrun[r] = mc;
            lnew[r] = 0.f;
        }
#pragma unroll
        for (int cg = 0; cg < 4; ++cg)
#pragma unroll
            for (int r = 0; r < 4; ++r) {
                float p = exp2f((sv[cg][r] - mrun[r]) * L2E);
                uint16_t pb = f2bf(p);
                Plds[w][(lg * 4 + r) * 72 + cg * 16 + lr] = pb;
                lnew[r] += bf2f(pb);
            }
#pragma unroll
        for (int off = 1; off < 16; off <<= 1)
#pragma unroll
            for (int r = 0; r < 4; ++r)
                lnew[r] += __shfl_xor(lnew[r], off, 64);
#pragma unroll
        for (int r = 0; r < 4; ++r) lrun[r] = lrun[r] * corr[r] + lnew[r];
#pragma unroll
        for (int i = 0; i < 8; ++i)
#pragma unroll
            for (int r = 0; r < 4; ++r) accO[i][r] *= corr[r];

        asm volatile("" ::: "memory");               // order P stores before reads
        bf16x8 pf[2];
#pragma unroll
        for (int c = 0; c < 2; ++c)
            pf[c] = *(const bf16x8*)(&Plds[w][lr * 72 + c * 32 + lg * 8]);
#pragma unroll
        for (int ni = 0; ni < 8; ++ni)
#pragma unroll
            for (int c = 0; c < 2; ++c) {
                bf16x8 vf = *(const bf16x8*)(&Vlds[(ni * 16 + lr) * 72 + c * 32 + lg * 8]);
                accO[ni] = __builtin_amdgcn_mfma_f32_16x16x32_bf16(pf[c], vf, accO[ni], 0, 0, 0);
            }
    }

    float inv[4];
#pragma unroll
    for (int r = 0; r < 4; ++r) inv[r] = 1.f / lrun[r];
    const int b = h >> 3, n = h & 7;
#pragma unroll
    for (int ni = 0; ni < 8; ++ni)
#pragma unroll
        for (int r = 0; r < 4; ++r) {
            int trow = q0 + w * 16 + lg * 4 + r;
            AOg[((size_t)(b * 2048 + trow)) * 1024 + n * 128 + ni * 16 + lr] =
                f2bf(accO[ni][r] * inv[r]);
        }
}

// ------------------------------------------------------- blade mixing epilogue
__global__ __launch_bounds__(256) void k_mix(const float* __restrict__ out,
                                             const float* __restrict__ alpha,
                                             float* __restrict__ fin) {
    constexpr int SI[42] = {1,1,1,1,1,1, 2,2,2,2,2,2, 3,3,3,3,3,3, 4,4,4,4,4,4,
                            5,5,5,5,5,5, 6,6,6,6,6,6, 7,7,7,7,7,7};
    constexpr int SJ[42] = {2,3,4,5,6,7, 1,3,4,5,6,7, 1,2,4,5,6,7, 1,2,3,5,6,7,
                            1,2,3,4,6,7, 1,2,3,4,5,7, 1,2,3,4,5,6};
    constexpr int TG[42] = {4,5,2,3,7,6, 4,6,1,7,3,5, 5,6,7,1,2,4, 2,1,7,6,5,3,
                            3,7,1,6,4,2, 7,3,2,5,4,1, 6,5,4,3,2,1};
    constexpr float SG[42] = {+1,+1,+1,+1,+1,+1, -1,+1,-1,-1,+1,-1, -1,-1,+1,-1,-1,+1,
                              -1,+1,+1,-1,+1,-1, -1,-1,+1,+1,-1,+1, +1,-1,+1,-1,+1,-1,
                              +1,-1,+1,-1,+1,-1};
    int idx = blockIdx.x * 256 + threadIdx.x;        // B*T * D
    int d = idx & 127, bt = idx >> 7;
    size_t base = (size_t)bt * 1024 + d;
    float o[8], r[8];
#pragma unroll
    for (int hh = 0; hh < 8; ++hh) { o[hh] = out[base + hh * 128]; r[hh] = o[hh]; }
#pragma unroll
    for (int p = 0; p < 42; ++p)
        r[TG[p]] += alpha[SI[p] * 8 + SJ[p]] * SG[p] * o[SI[p]] * o[SJ[p]];
#pragma unroll
    for (int hh = 0; hh < 8; ++hh) fin[base + hh * 128] = r[hh];
}

// ---------------------------------------------------------------------------
extern "C" void kernel_launch(void* const* d_in, const int* in_sizes, int n_in,
                              void* d_out, int out_size, void* d_ws, size_t ws_size,
                              hipStream_t stream) {
    (void)in_sizes; (void)n_in; (void)out_size; (void)ws_size;
    const float* mv    = (const float*)d_in[0];
    const float* Wqkv  = (const float*)d_in[1];
    const float* Wo    = (const float*)d_in[2];
    const float* alpha = (const float*)d_in[3];
    float* outp = (float*)d_out;
    char* ws = (char*)d_ws;

    // workspace layout (bytes); AO overlays Xbf, outF overlays QKV
    uint16_t* Xbf  = (uint16_t*)(ws + 0);            //  8 MB  [4096][1024]
    uint16_t* Wqt  = (uint16_t*)(ws + 8388608);      //  6 MB  [3072][1024]
    uint16_t* Wot  = (uint16_t*)(ws + 14680064);     //  2 MB  [1024][1024]
    uint16_t* QKV  = (uint16_t*)(ws + 16777216);     // 24 MB  [4096][3072]
    uint16_t* Qr   = (uint16_t*)(ws + 41943040);     //  8 MB  [16][2048][128]
    uint16_t* Kr   = (uint16_t*)(ws + 50331648);     //  8 MB
    uint16_t* Vt   = (uint16_t*)(ws + 58720256);     //  8 MB  [16][128][2048]
    float*    ctab = (float*)(ws + 67108864);        // 0.5 MB
    float*    stab = (float*)(ws + 67633152);        // 0.5 MB
    uint16_t* AO   = (uint16_t*)(ws + 0);            // overlay (X dead after GEMM1)
    float*    outF = (float*)(ws + 16777216);        // overlay (QKV dead after rope/vtrans)

    k_cast  <<<4096, 256, 0, stream>>>(mv, Xbf, 4096 * 1024);
    k_wtrans<<<dim3(48, 16), 256, 0, stream>>>(Wqkv, Wqt, 1024, 3072);
    k_wtrans<<<dim3(16, 16), 256, 0, stream>>>(Wo, Wot, 1024, 1024);
    k_tab   <<<512, 256, 0, stream>>>(ctab, stab);
    k_gemm<uint16_t><<<dim3(24, 32), 256, 0, stream>>>(Xbf, Wqt, QKV, 4096, 3072, 1024);
    k_rope  <<<8192, 256, 0, stream>>>(QKV, ctab, stab, Qr, Kr);
    k_vtrans<<<dim3(2, 32, 16), 256, 0, stream>>>(QKV, Vt);
    k_attn  <<<512, 256, 0, stream>>>(Qr, Kr, Vt, AO);
    k_gemm<float><<<dim3(8, 32), 256, 0, stream>>>(AO, Wot, outF, 4096, 1024, 1024);
    k_mix   <<<2048, 256, 0, stream>>>(outF, alpha, outp);
}

// Round 2
// 158.178 us; speedup vs baseline: 1.2504x; 1.2504x over previous
//
#include <hip/hip_runtime.h>
#include <stdint.h>

// ---------------------------------------------------------------------------
// GeometricAttention: x@Wqkv -> RoPE -> causal MHA -> @Wo -> blade mixing
// B=2 T=2048 N=8 D=128, d_model=1024. bf16 MFMA pipeline, fp32 accum.
// ---------------------------------------------------------------------------

typedef __attribute__((ext_vector_type(8))) __bf16 bf16x8;
typedef __attribute__((ext_vector_type(4))) float  f32x4;

__device__ __forceinline__ uint16_t f2bf(float f) {
    uint32_t u = __float_as_uint(f);
    u += 0x7FFFu + ((u >> 16) & 1u);           // RNE
    return (uint16_t)(u >> 16);
}
__device__ __forceinline__ float bf2f(uint16_t h) {
    return __uint_as_float(((uint32_t)h) << 16);
}

__device__ __forceinline__ void gload_lds16(const void* g, void* l) {
    __builtin_amdgcn_global_load_lds(
        (__attribute__((address_space(1))) void*)g,
        (__attribute__((address_space(3))) void*)l, 16, 0, 0);
}

__device__ __forceinline__ void store_out(uint16_t* p, float v) { *p = f2bf(v); }
__device__ __forceinline__ void store_out(float* p, float v)    { *p = v; }

// ---------------------------------------------------------------- cast fp32->bf16
__global__ __launch_bounds__(256) void k_cast(const float* __restrict__ in,
                                              uint16_t* __restrict__ out, int n) {
    int i = blockIdx.x * 256 + threadIdx.x;          // one float4 per thread
    if (i * 4 >= n) return;
    float4 v = ((const float4*)in)[i];
    ushort4 o = make_ushort4(f2bf(v.x), f2bf(v.y), f2bf(v.z), f2bf(v.w));
    ((ushort4*)out)[i] = o;
}

// ------------------------------------------------- transpose W [K][N] -> Wt [N][K] bf16
__global__ __launch_bounds__(256) void k_wtrans(const float* __restrict__ W,
                                                uint16_t* __restrict__ Wt,
                                                int K, int N) {
    __shared__ uint16_t tile[64][65];
    const int k0 = blockIdx.y * 64, n0 = blockIdx.x * 64;
    const int c = threadIdx.x & 63, r4 = threadIdx.x >> 6;
#pragma unroll
    for (int i = 0; i < 16; ++i) {
        int r = r4 + i * 4;
        tile[r][c] = f2bf(W[(size_t)(k0 + r) * N + n0 + c]);
    }
    __syncthreads();
#pragma unroll
    for (int i = 0; i < 16; ++i) {
        int r = r4 + i * 4;
        Wt[(size_t)(n0 + r) * K + k0 + c] = tile[c][r];
    }
}

// ---------------------------------------------------------------- RoPE tables
__global__ __launch_bounds__(256) void k_tab(float* __restrict__ ct,
                                             float* __restrict__ st) {
    int i = blockIdx.x * 256 + threadIdx.x;          // 2048*64
    int t = i >> 6, f = i & 63;
    float inv = expf(-(float)f * 0.14391156830441f); // ln(10000)/64
    float ang = (float)t * inv;
    ct[i] = cosf(ang);
    st[i] = sinf(ang);
}

// ------------------------------------------------------- m97-style bf16 GEMM
// C[M][N] = A[M][K] * Bt[N][K]^T ; 128x128 tile, BK=32, 4 waves
template <typename OutT>
__global__ __launch_bounds__(256) void k_gemm(const uint16_t* __restrict__ A,
                                              const uint16_t* __restrict__ Bt,
                                              OutT* __restrict__ C,
                                              int M, int N, int K) {
    __shared__ uint16_t Atile[128 * 32];
    __shared__ uint16_t Btile[128 * 32];
    const int m0 = blockIdx.y << 7, n0 = blockIdx.x << 7;
    const int tid = threadIdx.x;
    const int l = tid & 63, w = tid >> 6;
    const int lr = l & 15, lg = l >> 4;
    const int wm = (w >> 1) << 6, wn = (w & 1) << 6;

    f32x4 acc[4][4];
#pragma unroll
    for (int i = 0; i < 4; ++i)
#pragma unroll
        for (int j = 0; j < 4; ++j) acc[i][j] = (f32x4){0.f, 0.f, 0.f, 0.f};

    const int nk = K >> 5;
    for (int kt = 0; kt < nk; ++kt) {
        const int k0 = kt << 5;
        __syncthreads();
#pragma unroll
        for (int c = 0; c < 4; ++c) {
            int idx = c * 256 + tid;                 // 0..1023, wave-contiguous
            if (idx < 512) {
                int r = idx >> 2, kc = (idx & 3) << 3;
                gload_lds16(A + (size_t)(m0 + r) * K + k0 + kc, &Atile[idx * 8]);
            } else {
                int i2 = idx - 512;
                int r = i2 >> 2, kc = (i2 & 3) << 3;
                gload_lds16(Bt + (size_t)(n0 + r) * K + k0 + kc, &Btile[i2 * 8]);
            }
        }
        __syncthreads();
        bf16x8 af[4], bfv[4];
#pragma unroll
        for (int i = 0; i < 4; ++i) {
            af[i]  = *(const bf16x8*)(&Atile[(wm + i * 16 + lr) * 32 + lg * 8]);
            bfv[i] = *(const bf16x8*)(&Btile[(wn + i * 16 + lr) * 32 + lg * 8]);
        }
#pragma unroll
        for (int mi = 0; mi < 4; ++mi)
#pragma unroll
            for (int ni = 0; ni < 4; ++ni)
                acc[mi][ni] = __builtin_amdgcn_mfma_f32_16x16x32_bf16(
                    af[mi], bfv[ni], acc[mi][ni], 0, 0, 0);
    }
    // C/D layout: col = lane&15, row = (lane>>4)*4 + reg   [m89-verified]
#pragma unroll
    for (int mi = 0; mi < 4; ++mi)
#pragma unroll
        for (int ni = 0; ni < 4; ++ni)
#pragma unroll
            for (int r = 0; r < 4; ++r) {
                int row = m0 + wm + mi * 16 + lg * 4 + r;
                int col = n0 + wn + ni * 16 + lr;
                store_out(&C[(size_t)row * N + col], acc[mi][ni][r]);
            }
}

// ------------------------------------------- RoPE apply: QKV -> Q,K [h][T][D]
__global__ __launch_bounds__(256) void k_rope(const uint16_t* __restrict__ qkv,
                                              const float* __restrict__ ct,
                                              const float* __restrict__ st,
                                              uint16_t* __restrict__ Qo,
                                              uint16_t* __restrict__ Ko) {
    int idx = blockIdx.x * 256 + threadIdx.x;        // B*T*N*64 pairs
    int d  = idx & 63;
    int n  = (idx >> 6) & 7;
    int bt = idx >> 9;
    int t  = bt & 2047, b = bt >> 11;
    float c = ct[t * 64 + d], s = st[t * 64 + d];
    size_t base = (size_t)bt * 3072 + n * 128 + d;
    float q1 = bf2f(qkv[base]),        q2 = bf2f(qkv[base + 64]);
    float k1 = bf2f(qkv[base + 1024]), k2 = bf2f(qkv[base + 1024 + 64]);
    size_t ob = ((size_t)(b * 8 + n) * 2048 + t) * 128 + d;
    Qo[ob]      = f2bf(q1 * c - q2 * s);
    Qo[ob + 64] = f2bf(q2 * c + q1 * s);
    Ko[ob]      = f2bf(k1 * c - k2 * s);
    Ko[ob + 64] = f2bf(k2 * c + k1 * s);
}

// -------------------------------------- V transpose: QKV v-part -> Vt [h][D][T]
__global__ __launch_bounds__(256) void k_vtrans(const uint16_t* __restrict__ qkv,
                                                uint16_t* __restrict__ Vt) {
    __shared__ uint16_t tile[64][65];
    const int h = blockIdx.z, b = h >> 3, n = h & 7;
    const int t0 = blockIdx.y * 64, d0 = blockIdx.x * 64;
    const int c = threadIdx.x & 63, r4 = threadIdx.x >> 6;
#pragma unroll
    for (int i = 0; i < 16; ++i) {
        int r = r4 + i * 4;                          // t offset
        tile[r][c] = qkv[(size_t)(b * 2048 + t0 + r) * 3072 + 2048 + n * 128 + d0 + c];
    }
    __syncthreads();
#pragma unroll
    for (int i = 0; i < 16; ++i) {
        int r = r4 + i * 4;                          // d offset
        Vt[((size_t)h * 128 + d0 + r) * 2048 + t0 + c] = tile[c][r];
    }
}

// --------------------------------------------------- causal flash attention
// 64 q-rows/block, 4 waves x 16 rows; KV tiles of 64.
// Double-buffered K/V via global_load_lds (linear dest, inverse-swizzled
// source, swizzled reads — rule 21). One raw barrier per KV tile; vmcnt(0)
// drains the PREVIOUS iteration's async loads (full overlap with compute).
// Online softmax with defer-max (T13): common path has no butterflies, no
// O-rescale; running row-sum kept lane-local, reduced once at the end.
__global__ __launch_bounds__(256) void k_attn(const uint16_t* __restrict__ Qg,
                                              const uint16_t* __restrict__ Kg,
                                              const uint16_t* __restrict__ Vtg,
                                              uint16_t* __restrict__ AOg) {
    __shared__ uint16_t Klds[2][64 * 128];           // 16 KB each, XOR-swizzled
    __shared__ uint16_t Vlds[2][128 * 64];           // 16 KB each, XOR-swizzled
    __shared__ uint16_t Plds[4][16 * 72];

    const int bx = blockIdx.x;
    const int h = bx & 15, qt = 31 - (bx >> 4);      // all heads' heavy tiles first
    const int q0 = qt * 64;
    const int tid = threadIdx.x;
    const int l = tid & 63, w = tid >> 6;
    const int lr = l & 15, lg = l >> 4;
    const size_t headTD = (size_t)h * (2048 * 128);
    const uint16_t* Kh = Kg + headTD;
    const uint16_t* Vh = Vtg + headTD;

    bf16x8 qf[4];
    {
        const uint16_t* qp = Qg + headTD + (size_t)(q0 + w * 16 + lr) * 128 + lg * 8;
#pragma unroll
        for (int kc = 0; kc < 4; ++kc) qf[kc] = *(const bf16x8*)(qp + kc * 32);
    }

    f32x4 accO[8];
#pragma unroll
    for (int i = 0; i < 8; ++i) accO[i] = (f32x4){0.f, 0.f, 0.f, 0.f};
    float mrun[4], lrun[4];                          // mrun in scaled-log2 domain
#pragma unroll
    for (int r = 0; r < 4; ++r) { mrun[r] = -1e30f; lrun[r] = 0.f; }

    const float SL2E = 0.08838834764831845f * 1.4426950408889634f; // scale*log2(e)
    const int   swz  = (lr & 7) << 4;                // per-lane read swizzle

    auto STAGE = [&](int buf, int k0) {
#pragma unroll
        for (int p = 0; p < 4; ++p) {                // K: 64x128 rows of 256B
            int u = p * 256 + tid;                   // 16B chunk id
            int row = u >> 4;
            int c16 = (u & 15) ^ (row & 7);          // inverse swizzle on SOURCE
            gload_lds16(Kh + (size_t)(k0 + row) * 128 + c16 * 8,
                        (char*)&Klds[buf][0] + u * 16);
        }
#pragma unroll
        for (int p = 0; p < 4; ++p) {                // V: 128x64 rows of 128B
            int u = p * 256 + tid;
            int d = u >> 3;
            int c8 = (u & 7) ^ (d & 7);
            gload_lds16(Vh + (size_t)d * 2048 + k0 + c8 * 8,
                        (char*)&Vlds[buf][0] + u * 16);
        }
    };

    STAGE(0, 0);                                     // prologue

    for (int kt = 0; kt <= qt; ++kt) {
        asm volatile("s_waitcnt vmcnt(0)" ::: "memory"); // tile kt's loads done
        __builtin_amdgcn_s_barrier();
        __builtin_amdgcn_sched_barrier(0);
        if (kt < qt) STAGE((kt + 1) & 1, (kt + 1) * 64); // async prefetch

        const char* Kb = (const char*)&Klds[kt & 1][0];
        const char* Vb = (const char*)&Vlds[kt & 1][0];

        // ---- S = Q K^T (raw, unscaled) -----------------------------------
        float sv[4][4];
        __builtin_amdgcn_s_setprio(1);
#pragma unroll
        for (int cg = 0; cg < 4; ++cg) {
            f32x4 a = (f32x4){0.f, 0.f, 0.f, 0.f};
#pragma unroll
            for (int kc = 0; kc < 4; ++kc) {
                int kb = (cg * 16 + lr) * 256 + ((kc * 64 + lg * 16) ^ swz);
                bf16x8 kf = *(const bf16x8*)(Kb + kb);
                a = __builtin_amdgcn_mfma_f32_16x16x32_bf16(qf[kc], kf, a, 0, 0, 0);
            }
#pragma unroll
            for (int r = 0; r < 4; ++r) sv[cg][r] = a[r];
        }
        __builtin_amdgcn_s_setprio(0);

        if (kt == qt) {                              // causal mask, diagonal tile
#pragma unroll
            for (int cg = 0; cg < 4; ++cg)
#pragma unroll
                for (int r = 0; r < 4; ++r) {
                    int grow = w * 16 + lg * 4 + r;
                    int gcol = cg * 16 + lr;
                    if (gcol > grow) sv[cg][r] = -1e30f;
                }
        }

        // ---- defer-max online softmax ------------------------------------
        float pml[4];
#pragma unroll
        for (int r = 0; r < 4; ++r)
            pml[r] = fmaxf(fmaxf(sv[0][r], sv[1][r]), fmaxf(sv[2][r], sv[3][r]));
        bool ok = true;
#pragma unroll
        for (int r = 0; r < 4; ++r) ok &= (pml[r] * SL2E <= mrun[r] + 11.f);
        if (!__all(ok)) {                            // rare: true max + rescale
            float mx[4];
#pragma unroll
            for (int r = 0; r < 4; ++r) mx[r] = pml[r];
#pragma unroll
            for (int off = 1; off < 16; off <<= 1)
#pragma unroll
                for (int r = 0; r < 4; ++r)
                    mx[r] = fmaxf(mx[r], __shfl_xor(mx[r], off, 64));
#pragma unroll
            for (int r = 0; r < 4; ++r) {
                float mn = fmaxf(mrun[r], mx[r] * SL2E);
                float corr = exp2f(mrun[r] - mn);
                mrun[r] = mn;
                lrun[r] *= corr;
#pragma unroll
                for (int i = 0; i < 8; ++i) accO[i][r] *= corr;
            }
        }
#pragma unroll
        for (int cg = 0; cg < 4; ++cg)
#pragma unroll
            for (int r = 0; r < 4; ++r) {
                float p = exp2f(fmaf(sv[cg][r], SL2E, -mrun[r]));
                uint16_t pb = f2bf(p);
                Plds[w][(lg * 4 + r) * 72 + cg * 16 + lr] = pb;
                lrun[r] += bf2f(pb);                 // lane-local partial sum
            }

        asm volatile("" ::: "memory");               // order P stores before reads
        bf16x8 pf[2];
#pragma unroll
        for (int c = 0; c < 2; ++c)
            pf[c] = *(const bf16x8*)(&Plds[w][lr * 72 + c * 32 + lg * 8]);

        __builtin_amdgcn_s_setprio(1);
#pragma unroll
        for (int ni = 0; ni < 8; ++ni)
#pragma unroll
            for (int c = 0; c < 2; ++c) {
                int vb = (ni * 16 + lr) * 128 + ((c * 64 + lg * 16) ^ swz);
                bf16x8 vf = *(const bf16x8*)(Vb + vb);
                accO[ni] = __builtin_amdgcn_mfma_f32_16x16x32_bf16(pf[c], vf, accO[ni], 0, 0, 0);
            }
        __builtin_amdgcn_s_setprio(0);
    }

    // final cross-lane sum of lane-local row sums (16 lanes share a row)
#pragma unroll
    for (int off = 1; off < 16; off <<= 1)
#pragma unroll
        for (int r = 0; r < 4; ++r) lrun[r] += __shfl_xor(lrun[r], off, 64);
    float inv[4];
#pragma unroll
    for (int r = 0; r < 4; ++r) inv[r] = 1.f / lrun[r];
    const int b = h >> 3, n = h & 7;
#pragma unroll
    for (int ni = 0; ni < 8; ++ni)
#pragma unroll
        for (int r = 0; r < 4; ++r) {
            int trow = q0 + w * 16 + lg * 4 + r;
            AOg[((size_t)(b * 2048 + trow)) * 1024 + n * 128 + ni * 16 + lr] =
                f2bf(accO[ni][r] * inv[r]);
        }
}

// ------------------------------------------------------- blade mixing epilogue
__global__ __launch_bounds__(256) void k_mix(const float* __restrict__ out,
                                             const float* __restrict__ alpha,
                                             float* __restrict__ fin) {
    constexpr int SI[42] = {1,1,1,1,1,1, 2,2,2,2,2,2, 3,3,3,3,3,3, 4,4,4,4,4,4,
                            5,5,5,5,5,5, 6,6,6,6,6,6, 7,7,7,7,7,7};
    constexpr int SJ[42] = {2,3,4,5,6,7, 1,3,4,5,6,7, 1,2,4,5,6,7, 1,2,3,5,6,7,
                            1,2,3,4,6,7, 1,2,3,4,5,7, 1,2,3,4,5,6};
    constexpr int TG[42] = {4,5,2,3,7,6, 4,6,1,7,3,5, 5,6,7,1,2,4, 2,1,7,6,5,3,
                            3,7,1,6,4,2, 7,3,2,5,4,1, 6,5,4,3,2,1};
    constexpr float SG[42] = {+1,+1,+1,+1,+1,+1, -1,+1,-1,-1,+1,-1, -1,-1,+1,-1,-1,+1,
                              -1,+1,+1,-1,+1,-1, -1,-1,+1,+1,-1,+1, +1,-1,+1,-1,+1,-1,
                              +1,-1,+1,-1,+1,-1};
    int idx = blockIdx.x * 256 + threadIdx.x;        // B*T * D
    int d = idx & 127, bt = idx >> 7;
    size_t base = (size_t)bt * 1024 + d;
    float o[8], r[8];
#pragma unroll
    for (int hh = 0; hh < 8; ++hh) { o[hh] = out[base + hh * 128]; r[hh] = o[hh]; }
#pragma unroll
    for (int p = 0; p < 42; ++p)
        r[TG[p]] += alpha[SI[p] * 8 + SJ[p]] * SG[p] * o[SI[p]] * o[SJ[p]];
#pragma unroll
    for (int hh = 0; hh < 8; ++hh) fin[base + hh * 128] = r[hh];
}

// ---------------------------------------------------------------------------
extern "C" void kernel_launch(void* const* d_in, const int* in_sizes, int n_in,
                              void* d_out, int out_size, void* d_ws, size_t ws_size,
                              hipStream_t stream) {
    (void)in_sizes; (void)n_in; (void)out_size; (void)ws_size;
    const float* mv    = (const float*)d_in[0];
    const float* Wqkv  = (const float*)d_in[1];
    const float* Wo    = (const float*)d_in[2];
    const float* alpha = (const float*)d_in[3];
    float* outp = (float*)d_out;
    char* ws = (char*)d_ws;

    // workspace layout (bytes); AO overlays Xbf, outF overlays QKV
    uint16_t* Xbf  = (uint16_t*)(ws + 0);            //  8 MB  [4096][1024]
    uint16_t* Wqt  = (uint16_t*)(ws + 8388608);      //  6 MB  [3072][1024]
    uint16_t* Wot  = (uint16_t*)(ws + 14680064);     //  2 MB  [1024][1024]
    uint16_t* QKV  = (uint16_t*)(ws + 16777216);     // 24 MB  [4096][3072]
    uint16_t* Qr   = (uint16_t*)(ws + 41943040);     //  8 MB  [16][2048][128]
    uint16_t* Kr   = (uint16_t*)(ws + 50331648);     //  8 MB
    uint16_t* Vt   = (uint16_t*)(ws + 58720256);     //  8 MB  [16][128][2048]
    float*    ctab = (float*)(ws + 67108864);        // 0.5 MB
    float*    stab = (float*)(ws + 67633152);        // 0.5 MB
    uint16_t* AO   = (uint16_t*)(ws + 0);            // overlay (X dead after GEMM1)
    float*    outF = (float*)(ws + 16777216);        // overlay (QKV dead after rope/vtrans)

    k_cast  <<<4096, 256, 0, stream>>>(mv, Xbf, 4096 * 1024);
    k_wtrans<<<dim3(48, 16), 256, 0, stream>>>(Wqkv, Wqt, 1024, 3072);
    k_wtrans<<<dim3(16, 16), 256, 0, stream>>>(Wo, Wot, 1024, 1024);
    k_tab   <<<512, 256, 0, stream>>>(ctab, stab);
    k_gemm<uint16_t><<<dim3(24, 32), 256, 0, stream>>>(Xbf, Wqt, QKV, 4096, 3072, 1024);
    k_rope  <<<8192, 256, 0, stream>>>(QKV, ctab, stab, Qr, Kr);
    k_vtrans<<<dim3(2, 32, 16), 256, 0, stream>>>(QKV, Vt);
    k_attn  <<<512, 256, 0, stream>>>(Qr, Kr, Vt, AO);
    k_gemm<float><<<dim3(8, 32), 256, 0, stream>>>(AO, Wot, outF, 4096, 1024, 1024);
    k_mix   <<<2048, 256, 0, stream>>>(outF, alpha, outp);
}

// Round 3
// 150.629 us; speedup vs baseline: 1.3131x; 1.0501x over previous
//
#include <hip/hip_runtime.h>
#include <stdint.h>

// ---------------------------------------------------------------------------
// GeometricAttention: x@Wqkv -> RoPE -> causal MHA -> @Wo -> blade mixing
// B=2 T=2048 N=8 D=128, d_model=1024. bf16 MFMA pipeline, fp32 accum.
// ---------------------------------------------------------------------------

typedef __attribute__((ext_vector_type(8))) __bf16 bf16x8;
typedef __attribute__((ext_vector_type(4))) float  f32x4;

__device__ __forceinline__ uint16_t f2bf(float f) {
    uint32_t u = __float_as_uint(f);
    u += 0x7FFFu + ((u >> 16) & 1u);           // RNE
    return (uint16_t)(u >> 16);
}
__device__ __forceinline__ float bf2f(uint16_t h) {
    return __uint_as_float(((uint32_t)h) << 16);
}

__device__ __forceinline__ void gload_lds16(const void* g, void* l) {
    __builtin_amdgcn_global_load_lds(
        (__attribute__((address_space(1))) void*)g,
        (__attribute__((address_space(3))) void*)l, 16, 0, 0);
}

__device__ __forceinline__ void store_out(uint16_t* p, float v) { *p = f2bf(v); }
__device__ __forceinline__ void store_out(float* p, float v)    { *p = v; }

// ---------------------------------------------------------------- cast fp32->bf16
__global__ __launch_bounds__(256) void k_cast(const float* __restrict__ in,
                                              uint16_t* __restrict__ out, int n) {
    int i = blockIdx.x * 256 + threadIdx.x;          // one float4 per thread
    if (i * 4 >= n) return;
    float4 v = ((const float4*)in)[i];
    ushort4 o = make_ushort4(f2bf(v.x), f2bf(v.y), f2bf(v.z), f2bf(v.w));
    ((ushort4*)out)[i] = o;
}

// ------------------------------------------------- transpose W [K][N] -> Wt [N][K] bf16
__global__ __launch_bounds__(256) void k_wtrans(const float* __restrict__ W,
                                                uint16_t* __restrict__ Wt,
                                                int K, int N) {
    __shared__ uint16_t tile[64][65];
    const int k0 = blockIdx.y * 64, n0 = blockIdx.x * 64;
    const int c = threadIdx.x & 63, r4 = threadIdx.x >> 6;
#pragma unroll
    for (int i = 0; i < 16; ++i) {
        int r = r4 + i * 4;
        tile[r][c] = f2bf(W[(size_t)(k0 + r) * N + n0 + c]);
    }
    __syncthreads();
#pragma unroll
    for (int i = 0; i < 16; ++i) {
        int r = r4 + i * 4;
        Wt[(size_t)(n0 + r) * K + k0 + c] = tile[c][r];
    }
}

// ---------------------------------------------------------------- RoPE tables
__global__ __launch_bounds__(256) void k_tab(float* __restrict__ ct,
                                             float* __restrict__ st) {
    int i = blockIdx.x * 256 + threadIdx.x;          // 2048*64
    int t = i >> 6, f = i & 63;
    float inv = expf(-(float)f * 0.14391156830441f); // ln(10000)/64
    float ang = (float)t * inv;
    ct[i] = cosf(ang);
    st[i] = sinf(ang);
}

// ------------------------------------------------------- m97-style bf16 GEMM
// C[M][N] = A[M][K] * Bt[N][K]^T ; 128x128 tile, BK=32, 4 waves
template <typename OutT>
__global__ __launch_bounds__(256) void k_gemm(const uint16_t* __restrict__ A,
                                              const uint16_t* __restrict__ Bt,
                                              OutT* __restrict__ C,
                                              int M, int N, int K) {
    __shared__ uint16_t Atile[128 * 32];
    __shared__ uint16_t Btile[128 * 32];
    const int m0 = blockIdx.y << 7, n0 = blockIdx.x << 7;
    const int tid = threadIdx.x;
    const int l = tid & 63, w = tid >> 6;
    const int lr = l & 15, lg = l >> 4;
    const int wm = (w >> 1) << 6, wn = (w & 1) << 6;

    f32x4 acc[4][4];
#pragma unroll
    for (int i = 0; i < 4; ++i)
#pragma unroll
        for (int j = 0; j < 4; ++j) acc[i][j] = (f32x4){0.f, 0.f, 0.f, 0.f};

    const int nk = K >> 5;
    for (int kt = 0; kt < nk; ++kt) {
        const int k0 = kt << 5;
        __syncthreads();
#pragma unroll
        for (int c = 0; c < 4; ++c) {
            int idx = c * 256 + tid;                 // 0..1023, wave-contiguous
            if (idx < 512) {
                int r = idx >> 2, kc = (idx & 3) << 3;
                gload_lds16(A + (size_t)(m0 + r) * K + k0 + kc, &Atile[idx * 8]);
            } else {
                int i2 = idx - 512;
                int r = i2 >> 2, kc = (i2 & 3) << 3;
                gload_lds16(Bt + (size_t)(n0 + r) * K + k0 + kc, &Btile[i2 * 8]);
            }
        }
        __syncthreads();
        bf16x8 af[4], bfv[4];
#pragma unroll
        for (int i = 0; i < 4; ++i) {
            af[i]  = *(const bf16x8*)(&Atile[(wm + i * 16 + lr) * 32 + lg * 8]);
            bfv[i] = *(const bf16x8*)(&Btile[(wn + i * 16 + lr) * 32 + lg * 8]);
        }
#pragma unroll
        for (int mi = 0; mi < 4; ++mi)
#pragma unroll
            for (int ni = 0; ni < 4; ++ni)
                acc[mi][ni] = __builtin_amdgcn_mfma_f32_16x16x32_bf16(
                    af[mi], bfv[ni], acc[mi][ni], 0, 0, 0);
    }
    // C/D layout: col = lane&15, row = (lane>>4)*4 + reg   [m89-verified]
#pragma unroll
    for (int mi = 0; mi < 4; ++mi)
#pragma unroll
        for (int ni = 0; ni < 4; ++ni)
#pragma unroll
            for (int r = 0; r < 4; ++r) {
                int row = m0 + wm + mi * 16 + lg * 4 + r;
                int col = n0 + wn + ni * 16 + lr;
                store_out(&C[(size_t)row * N + col], acc[mi][ni][r]);
            }
}

// ------------------------------------------- RoPE apply: QKV -> Q,K [h][T][D]
__global__ __launch_bounds__(256) void k_rope(const uint16_t* __restrict__ qkv,
                                              const float* __restrict__ ct,
                                              const float* __restrict__ st,
                                              uint16_t* __restrict__ Qo,
                                              uint16_t* __restrict__ Ko) {
    int idx = blockIdx.x * 256 + threadIdx.x;        // B*T*N*64 pairs
    int d  = idx & 63;
    int n  = (idx >> 6) & 7;
    int bt = idx >> 9;
    int t  = bt & 2047, b = bt >> 11;
    float c = ct[t * 64 + d], s = st[t * 64 + d];
    size_t base = (size_t)bt * 3072 + n * 128 + d;
    float q1 = bf2f(qkv[base]),        q2 = bf2f(qkv[base + 64]);
    float k1 = bf2f(qkv[base + 1024]), k2 = bf2f(qkv[base + 1024 + 64]);
    size_t ob = ((size_t)(b * 8 + n) * 2048 + t) * 128 + d;
    Qo[ob]      = f2bf(q1 * c - q2 * s);
    Qo[ob + 64] = f2bf(q2 * c + q1 * s);
    Ko[ob]      = f2bf(k1 * c - k2 * s);
    Ko[ob + 64] = f2bf(k2 * c + k1 * s);
}

// -------------------------------------- V transpose: QKV v-part -> Vt [h][D][T]
__global__ __launch_bounds__(256) void k_vtrans(const uint16_t* __restrict__ qkv,
                                                uint16_t* __restrict__ Vt) {
    __shared__ uint16_t tile[64][65];
    const int h = blockIdx.z, b = h >> 3, n = h & 7;
    const int t0 = blockIdx.y * 64, d0 = blockIdx.x * 64;
    const int c = threadIdx.x & 63, r4 = threadIdx.x >> 6;
#pragma unroll
    for (int i = 0; i < 16; ++i) {
        int r = r4 + i * 4;                          // t offset
        tile[r][c] = qkv[(size_t)(b * 2048 + t0 + r) * 3072 + 2048 + n * 128 + d0 + c];
    }
    __syncthreads();
#pragma unroll
    for (int i = 0; i < 16; ++i) {
        int r = r4 + i * 4;                          // d offset
        Vt[((size_t)h * 128 + d0 + r) * 2048 + t0 + c] = tile[c][r];
    }
}

// --------------------------------------------------- causal flash attention
// Swapped QK^T (S^T = mfma(K,Q)) so each lane holds P[q=lr][16 k] lane-locally:
// softmax state is scalar/lane, common path has NO cross-lane ops. P goes to
// LDS as packed b64 (cvt_pk_bf16 pairs), read back as swizzled b128 A-frags.
// K/V double-buffered via global_load_lds (linear dest, inverse-swizzled src).
// Balanced causal schedule: blocks bx and bx+256 (same CU, same head under
// round-robin) get qt pairs summing to 33 tile-iters.
__global__ __launch_bounds__(256) void k_attn(const uint16_t* __restrict__ Qg,
                                              const uint16_t* __restrict__ Kg,
                                              const uint16_t* __restrict__ Vtg,
                                              uint16_t* __restrict__ AOg) {
    __shared__ uint16_t Klds[2][64 * 128];           // 16 KB each, XOR-swizzled
    __shared__ uint16_t Vlds[2][128 * 64];           // 16 KB each, XOR-swizzled
    __shared__ uint16_t Plds[4][16 * 64];            // 2 KB per wave, swizzled

    const int bx = blockIdx.x;
    const int h  = bx & 15;
    const int t4 = (bx >> 4) & 15;
    const int qt = (bx < 256) ? (31 - t4) : t4;      // heavy/light pairing
    const int q0 = qt * 64;
    const int tid = threadIdx.x;
    const int l = tid & 63, w = tid >> 6;
    const int lr = l & 15, lg = l >> 4;
    const size_t headTD = (size_t)h * (2048 * 128);
    const uint16_t* Kh = Kg + headTD;
    const uint16_t* Vh = Vtg + headTD;

    bf16x8 qf[4];
    {
        const uint16_t* qp = Qg + headTD + (size_t)(q0 + w * 16 + lr) * 128 + lg * 8;
#pragma unroll
        for (int kc = 0; kc < 4; ++kc) qf[kc] = *(const bf16x8*)(qp + kc * 32);
    }

    f32x4 accO[8];
#pragma unroll
    for (int i = 0; i < 8; ++i) accO[i] = (f32x4){0.f, 0.f, 0.f, 0.f};
    float mrun = -1e30f, lrun = 0.f;                 // per-lane row q = lr

    const float SL2E = 0.08838834764831845f * 1.4426950408889634f; // scale*log2e
    const int   swz  = (lr & 7) << 4;                // per-lane swizzle (row=lr)
    uint16_t* Pw = &Plds[w][0];

    auto STAGE = [&](int buf, int k0) {
#pragma unroll
        for (int p = 0; p < 4; ++p) {                // K: 64x128 rows of 256B
            int u = p * 256 + tid;                   // 16B chunk id
            int row = u >> 4;
            int c16 = (u & 15) ^ (row & 7);          // inverse swizzle on SOURCE
            gload_lds16(Kh + (size_t)(k0 + row) * 128 + c16 * 8,
                        (char*)&Klds[buf][0] + u * 16);
        }
#pragma unroll
        for (int p = 0; p < 4; ++p) {                // V: 128x64 rows of 128B
            int u = p * 256 + tid;
            int d = u >> 3;
            int c8 = (u & 7) ^ (d & 7);
            gload_lds16(Vh + (size_t)d * 2048 + k0 + c8 * 8,
                        (char*)&Vlds[buf][0] + u * 16);
        }
    };

    STAGE(0, 0);                                     // prologue

    for (int kt = 0; kt <= qt; ++kt) {
        asm volatile("s_waitcnt vmcnt(0)" ::: "memory"); // tile kt's loads done
        __builtin_amdgcn_s_barrier();
        __builtin_amdgcn_sched_barrier(0);
        if (kt < qt) STAGE((kt + 1) & 1, (kt + 1) * 64); // async prefetch

        const char* Kb = (const char*)&Klds[kt & 1][0];
        const char* Vb = (const char*)&Vlds[kt & 1][0];

        // ---- S^T = K Q^T : lane holds S[q=lr][k = cg*16 + lg*4 + r] ------
        float sv[4][4];
        __builtin_amdgcn_s_setprio(1);
#pragma unroll
        for (int cg = 0; cg < 4; ++cg) {
            f32x4 a = (f32x4){0.f, 0.f, 0.f, 0.f};
#pragma unroll
            for (int kc = 0; kc < 4; ++kc) {
                int kb = (cg * 16 + lr) * 256 + ((kc * 64 + lg * 16) ^ swz);
                bf16x8 kf = *(const bf16x8*)(Kb + kb);
                a = __builtin_amdgcn_mfma_f32_16x16x32_bf16(kf, qf[kc], a, 0, 0, 0);
            }
#pragma unroll
            for (int r = 0; r < 4; ++r) sv[cg][r] = a[r];
        }
        __builtin_amdgcn_s_setprio(0);

        if (kt == qt) {                              // causal mask, diagonal tile
#pragma unroll
            for (int cg = 0; cg < 4; ++cg)
#pragma unroll
                for (int r = 0; r < 4; ++r)
                    if (cg * 16 + lg * 4 + r > w * 16 + lr) sv[cg][r] = -1e30f;
        }

        // ---- defer-max online softmax (lane-local row) -------------------
        float pml = sv[0][0];
#pragma unroll
        for (int cg = 0; cg < 4; ++cg)
#pragma unroll
            for (int r = 0; r < 4; ++r) pml = fmaxf(pml, sv[cg][r]);

        if (!__all(pml * SL2E <= mrun + 11.f)) {     // rare: true max + rescale
            float mx = pml;
            mx = fmaxf(mx, __shfl_xor(mx, 16, 64));
            mx = fmaxf(mx, __shfl_xor(mx, 32, 64));  // full row max (q = lr)
            float mn = fmaxf(mrun, mx * SL2E);
            float corr = exp2f(mrun - mn);
            mrun = mn;
            lrun *= corr;                            // lane-partial sum scales too
            float ca[4];
#pragma unroll
            for (int r = 0; r < 4; ++r)              // corr for accO rows q=lg*4+r
                ca[r] = __shfl(corr, (lg << 4) + lg * 4 + r, 64);
#pragma unroll
            for (int i = 0; i < 8; ++i)
#pragma unroll
                for (int r = 0; r < 4; ++r) accO[i][r] *= ca[r];
        }

        float psum = 0.f;
        float p[4][4];
#pragma unroll
        for (int cg = 0; cg < 4; ++cg)
#pragma unroll
            for (int r = 0; r < 4; ++r) {
                p[cg][r] = exp2f(fmaf(sv[cg][r], SL2E, -mrun));
                psum += p[cg][r];
            }
        lrun += psum;

        // pack P pairs -> b64 LDS writes (row q=lr, k = 16cg+4lg .. +3)
#pragma unroll
        for (int cg = 0; cg < 4; ++cg) {
            uint32_t w0, w1;
            asm("v_cvt_pk_bf16_f32 %0, %1, %2" : "=v"(w0) : "v"(p[cg][0]), "v"(p[cg][1]));
            asm("v_cvt_pk_bf16_f32 %0, %1, %2" : "=v"(w1) : "v"(p[cg][2]), "v"(p[cg][3]));
            uint2 pr; pr.x = w0; pr.y = w1;
            *(uint2*)((char*)Pw + lr * 128 + ((cg * 32 + lg * 8) ^ swz)) = pr;
        }

        asm volatile("" ::: "memory");               // order P stores before reads
        bf16x8 pf[2];
#pragma unroll
        for (int c = 0; c < 2; ++c)
            pf[c] = *(const bf16x8*)((char*)Pw + lr * 128 + ((c * 64 + lg * 16) ^ swz));

        __builtin_amdgcn_s_setprio(1);
#pragma unroll
        for (int ni = 0; ni < 8; ++ni)
#pragma unroll
            for (int c = 0; c < 2; ++c) {
                int vb = (ni * 16 + lr) * 128 + ((c * 64 + lg * 16) ^ swz);
                bf16x8 vf = *(const bf16x8*)(Vb + vb);
                accO[ni] = __builtin_amdgcn_mfma_f32_16x16x32_bf16(pf[c], vf, accO[ni], 0, 0, 0);
            }
        __builtin_amdgcn_s_setprio(0);
    }

    // row sums: reduce lane-partials across the 4 lg lanes, then redistribute
    float lsum = lrun;
    lsum += __shfl_xor(lsum, 16, 64);
    lsum += __shfl_xor(lsum, 32, 64);                // full sum for row q = lr
    float linv = 1.f / lsum;
    float inv[4];
#pragma unroll
    for (int r = 0; r < 4; ++r)
        inv[r] = __shfl(linv, (lg << 4) + lg * 4 + r, 64); // for rows q=lg*4+r
    const int b = h >> 3, n = h & 7;
#pragma unroll
    for (int ni = 0; ni < 8; ++ni)
#pragma unroll
        for (int r = 0; r < 4; ++r) {
            int trow = q0 + w * 16 + lg * 4 + r;
            AOg[((size_t)(b * 2048 + trow)) * 1024 + n * 128 + ni * 16 + lr] =
                f2bf(accO[ni][r] * inv[r]);
        }
}

// ------------------------------------------------------- blade mixing epilogue
__global__ __launch_bounds__(256) void k_mix(const float* __restrict__ out,
                                             const float* __restrict__ alpha,
                                             float* __restrict__ fin) {
    constexpr int SI[42] = {1,1,1,1,1,1, 2,2,2,2,2,2, 3,3,3,3,3,3, 4,4,4,4,4,4,
                            5,5,5,5,5,5, 6,6,6,6,6,6, 7,7,7,7,7,7};
    constexpr int SJ[42] = {2,3,4,5,6,7, 1,3,4,5,6,7, 1,2,4,5,6,7, 1,2,3,5,6,7,
                            1,2,3,4,6,7, 1,2,3,4,5,7, 1,2,3,4,5,6};
    constexpr int TG[42] = {4,5,2,3,7,6, 4,6,1,7,3,5, 5,6,7,1,2,4, 2,1,7,6,5,3,
                            3,7,1,6,4,2, 7,3,2,5,4,1, 6,5,4,3,2,1};
    constexpr float SG[42] = {+1,+1,+1,+1,+1,+1, -1,+1,-1,-1,+1,-1, -1,-1,+1,-1,-1,+1,
                              -1,+1,+1,-1,+1,-1, -1,-1,+1,+1,-1,+1, +1,-1,+1,-1,+1,-1,
                              +1,-1,+1,-1,+1,-1};
    int idx = blockIdx.x * 256 + threadIdx.x;        // B*T * D
    int d = idx & 127, bt = idx >> 7;
    size_t base = (size_t)bt * 1024 + d;
    float o[8], r[8];
#pragma unroll
    for (int hh = 0; hh < 8; ++hh) { o[hh] = out[base + hh * 128]; r[hh] = o[hh]; }
#pragma unroll
    for (int p = 0; p < 42; ++p)
        r[TG[p]] += alpha[SI[p] * 8 + SJ[p]] * SG[p] * o[SI[p]] * o[SJ[p]];
#pragma unroll
    for (int hh = 0; hh < 8; ++hh) fin[base + hh * 128] = r[hh];
}

// ---------------------------------------------------------------------------
extern "C" void kernel_launch(void* const* d_in, const int* in_sizes, int n_in,
                              void* d_out, int out_size, void* d_ws, size_t ws_size,
                              hipStream_t stream) {
    (void)in_sizes; (void)n_in; (void)out_size; (void)ws_size;
    const float* mv    = (const float*)d_in[0];
    const float* Wqkv  = (const float*)d_in[1];
    const float* Wo    = (const float*)d_in[2];
    const float* alpha = (const float*)d_in[3];
    float* outp = (float*)d_out;
    char* ws = (char*)d_ws;

    // workspace layout (bytes); AO overlays Xbf, outF overlays QKV
    uint16_t* Xbf  = (uint16_t*)(ws + 0);            //  8 MB  [4096][1024]
    uint16_t* Wqt  = (uint16_t*)(ws + 8388608);      //  6 MB  [3072][1024]
    uint16_t* Wot  = (uint16_t*)(ws + 14680064);     //  2 MB  [1024][1024]
    uint16_t* QKV  = (uint16_t*)(ws + 16777216);     // 24 MB  [4096][3072]
    uint16_t* Qr   = (uint16_t*)(ws + 41943040);     //  8 MB  [16][2048][128]
    uint16_t* Kr   = (uint16_t*)(ws + 50331648);     //  8 MB
    uint16_t* Vt   = (uint16_t*)(ws + 58720256);     //  8 MB  [16][128][2048]
    float*    ctab = (float*)(ws + 67108864);        // 0.5 MB
    float*    stab = (float*)(ws + 67633152);        // 0.5 MB
    uint16_t* AO   = (uint16_t*)(ws + 0);            // overlay (X dead after GEMM1)
    float*    outF = (float*)(ws + 16777216);        // overlay (QKV dead after rope/vtrans)

    k_cast  <<<4096, 256, 0, stream>>>(mv, Xbf, 4096 * 1024);
    k_wtrans<<<dim3(48, 16), 256, 0, stream>>>(Wqkv, Wqt, 1024, 3072);
    k_wtrans<<<dim3(16, 16), 256, 0, stream>>>(Wo, Wot, 1024, 1024);
    k_tab   <<<512, 256, 0, stream>>>(ctab, stab);
    k_gemm<uint16_t><<<dim3(24, 32), 256, 0, stream>>>(Xbf, Wqt, QKV, 4096, 3072, 1024);
    k_rope  <<<8192, 256, 0, stream>>>(QKV, ctab, stab, Qr, Kr);
    k_vtrans<<<dim3(2, 32, 16), 256, 0, stream>>>(QKV, Vt);
    k_attn  <<<512, 256, 0, stream>>>(Qr, Kr, Vt, AO);
    k_gemm<float><<<dim3(8, 32), 256, 0, stream>>>(AO, Wot, outF, 4096, 1024, 1024);
    k_mix   <<<2048, 256, 0, stream>>>(outF, alpha, outp);
}